// Round 15
// baseline (272.662 us; speedup 1.0000x reference)
//
#include <hip/hip_runtime.h>
#include <cstdint>
#include <cstddef>

typedef __attribute__((ext_vector_type(4))) float  f32x4;
typedef __attribute__((ext_vector_type(8))) short  s16x8;
typedef __attribute__((ext_vector_type(4))) short  s16x4;
typedef __attribute__((ext_vector_type(2))) unsigned int u32x2;

#define EMB   1024
#define NHEAD 16
#define HD    64
#define NB    2
#define TT    2048
#define TQKV  3072   // packed Q|K|V column count

// exp(x*0.125) == exp2(x*0.18033688)
#define C_EXP2 0.18033688011112042f

// ---------- helpers ----------
__device__ __forceinline__ short f2bf(float f) {
  union { float f; unsigned u; } x; x.f = f;
  unsigned r = x.u + 0x7FFFu + ((x.u >> 16) & 1u);
  return (short)(r >> 16);
}

__device__ __forceinline__ unsigned cvt_pk_bf16(float lo, float hi) {
  unsigned r;
  asm("v_cvt_pk_bf16_f32 %0, %1, %2" : "=v"(r) : "v"(lo), "v"(hi));
  return r;
}

__device__ __forceinline__ void gload_lds16(const short* g, short* l) {
  __builtin_amdgcn_global_load_lds(
      (const __attribute__((address_space(1))) void*)(g),
      (__attribute__((address_space(3))) void*)(l), 16, 0, 0);
}

// counted-waitcnt barriers (T4): never drain stores to 0 in the hot loop.
#define MAKE_BAR(NAME, N)                                          \
  __device__ __forceinline__ void NAME() {                         \
    asm volatile("s_waitcnt vmcnt(" #N ")" ::: "memory");          \
    __builtin_amdgcn_sched_barrier(0);                             \
    __builtin_amdgcn_s_barrier();                                  \
    __builtin_amdgcn_sched_barrier(0);                             \
  }
MAKE_BAR(bar_vm0, 0)
MAKE_BAR(bar_vm2, 2)
MAKE_BAR(bar_vm4, 4)
MAKE_BAR(bar_vm8, 8)
#undef MAKE_BAR

// ---------- fp32 -> bf16 convert, all inputs in one launch ----------
__global__ __launch_bounds__(256) void cvt_all(
    const float* __restrict__ x,  const float* __restrict__ wq,
    const float* __restrict__ wk, const float* __restrict__ wv,
    const float* __restrict__ wo,
    short* __restrict__ xb, short* __restrict__ wqkv, short* __restrict__ wob) {
  int i = blockIdx.x * 256 + threadIdx.x;   // quad index, 2097152 total
  const float* s; short* d; int off;
  if (i < 1048576) { s = x; d = xb; off = i; }
  else {
    int j = i - 1048576;
    int r = j >> 18;            // 0..3
    off = j & 262143;
    s = (r == 0) ? wq : (r == 1) ? wk : (r == 2) ? wv : wo;
    d = (r == 3) ? wob : wqkv + (size_t)r * 1048576;
  }
  f32x4 v = ((const f32x4*)s)[off];
  s16x4 o;
  o[0] = f2bf(v[0]); o[1] = f2bf(v[1]); o[2] = f2bf(v[2]); o[3] = f2bf(v[3]);
  ((s16x4*)d)[off] = o;
}

// ---------- GEMM  C[M,N] = A[M,K] @ B[N,K]^T  (bf16 in, f32 acc) ----------
// 128x128 tile, BK=32, 8 waves (2x4), per-wave 64x32 (4x2 frags).
// 3-buffer ring, 2-ahead staging, trailing vmcnt(2).
template <int OUT_BF16>
__global__ __launch_bounds__(512) void gemm_nt(const short* __restrict__ A,
                                               const short* __restrict__ B,
                                               void* __restrict__ C,
                                               int M, int N, int K) {
  __shared__ short lA[3][128 * 32];
  __shared__ short lB[3][128 * 32];
  const int tid  = threadIdx.x;
  const int lane = tid & 63;
  const int wid  = tid >> 6;                 // 0..7
  const int bm = blockIdx.y, bn = blockIdx.x;
  const int wm = wid >> 2, wn = wid & 3;     // 2 x 4 wave grid

  f32x4 acc[4][2];
#pragma unroll
  for (int i = 0; i < 4; ++i)
#pragma unroll
    for (int j = 0; j < 2; ++j) acc[i][j] = (f32x4){0.f, 0.f, 0.f, 0.f};

  const short* Ab = A + (size_t)bm * 128 * K;
  const short* Bb = B + (size_t)bn * 128 * K;
  const int srow = tid >> 2;                       // 0..127
  const int scol = (((tid & 3) ^ (srow & 3))) * 8; // pre-swizzled source group

#define G_STAGE(buf, k0)                                                     \
  do {                                                                       \
    gload_lds16(Ab + (size_t)srow * K + (k0) + scol, &lA[buf][tid * 8]);     \
    gload_lds16(Bb + (size_t)srow * K + (k0) + scol, &lB[buf][tid * 8]);     \
  } while (0)

  const int nk = K >> 5;                     // K-steps
  G_STAGE(0, 0);
  if (nk > 1) G_STAGE(1, 32);
  if (nk > 1) bar_vm2(); else bar_vm0();
  for (int p = 0; p < nk; ++p) {
    const int s = p % 3;
    const bool pre = (p + 2 < nk);
    if (pre) G_STAGE((p + 2) % 3, (p + 2) * 32);
    __builtin_amdgcn_sched_barrier(0);       // pin issue order for the FIFO

    s16x8 af[4], bf_[2];
#pragma unroll
    for (int i = 0; i < 4; ++i) {
      const int ra = wm * 64 + i * 16 + (lane & 15);
      af[i] = *(const s16x8*)(&lA[s][ra * 32 + (((lane >> 4) ^ (ra & 3)) << 3)]);
    }
#pragma unroll
    for (int j = 0; j < 2; ++j) {
      const int rb = wn * 32 + j * 16 + (lane & 15);
      bf_[j] = *(const s16x8*)(&lB[s][rb * 32 + (((lane >> 4) ^ (rb & 3)) << 3)]);
    }
    __builtin_amdgcn_s_setprio(1);
#pragma unroll
    for (int i = 0; i < 4; ++i)
#pragma unroll
      for (int j = 0; j < 2; ++j)
        acc[i][j] = __builtin_amdgcn_mfma_f32_16x16x32_bf16(af[i], bf_[j], acc[i][j], 0, 0, 0);
    __builtin_amdgcn_s_setprio(0);

    if (p + 1 < nk) { if (pre) bar_vm2(); else bar_vm0(); }
  }
#undef G_STAGE

  const int row0 = bm * 128 + wm * 64;
  const int col0 = bn * 128 + wn * 32;
#pragma unroll
  for (int i = 0; i < 4; ++i)
#pragma unroll
    for (int j = 0; j < 2; ++j)
#pragma unroll
      for (int r = 0; r < 4; ++r) {
        int row = row0 + i * 16 + ((lane >> 4) << 2) + r;
        int col = col0 + j * 16 + (lane & 15);
        float v = acc[i][j][r];
        if (OUT_BF16) ((short*)C)[(size_t)row * N + col] = f2bf(v);
        else          ((float*)C)[(size_t)row * N + col] = v;
      }
}

// ---------- V transpose: Vt[bh][d][t] ----------
__global__ __launch_bounds__(256) void transpose_v(const short* __restrict__ qkv,
                                                   short* __restrict__ vt) {
  __shared__ short tile[64 * 72];
  const int tt = blockIdx.x, bh = blockIdx.y;
  const int b = bh >> 4, h = bh & 15;
  const int tid = threadIdx.x;

  const short* src = qkv + ((size_t)(b * TT + tt * 64)) * TQKV + 2048 + h * HD;
#pragma unroll
  for (int p = 0; p < 2; ++p) {
    int r = p * 32 + (tid >> 3);
    int c = (tid & 7) * 8;
    s16x8 v = *(const s16x8*)(src + (size_t)r * TQKV + c);
#pragma unroll
    for (int j = 0; j < 8; ++j) tile[r * 72 + c + j] = v[j];
  }
  __syncthreads();
  short* dst = vt + ((size_t)bh * HD) * TT + tt * 64;
#pragma unroll
  for (int p = 0; p < 2; ++p) {
    int d0 = p * 32 + (tid >> 3);
    int c  = (tid & 7) * 8;
    s16x8 o;
#pragma unroll
    for (int j = 0; j < 8; ++j) o[j] = tile[(c + j) * 72 + d0];
    *(s16x8*)(dst + (size_t)d0 * TT + c) = o;
  }
}

// ---------- fused attention: QBLK=128, 8 waves, swapped QK^T, pairs -------
// m == 0 everywhere (scores bounded, fp32 exp headroom; shift-invariant).
// SWAPPED QK^T (r10): s2[kg]=mfma(K,Q) -> S[k][q]; w stored direct as f32x4.
// r15: zero-fill moved from kernel tail INTO phase 1 (chunked per
// iteration). Phase 1 previously issued no writes -> write pipe idle for
// ~40% of the kernel; now the zero half of w (268 MB grid-wide) streams
// during phase 1. Anti-correlated balance: zero volume (30-2qt tiles) vs
// phase-1 length (qt+1 pairs); CU pair (qt,15-qt) fills both windows.
// Cached stores issued at iteration START: oldest in the VMEM FIFO, so the
// trailing vmcnt(2) leaves the 2-ahead K-prefetch untouched and forces the
// zero stores only after a full loop body of latency (NOT r3's NT-store +
// vmcnt(0) collapse).
__global__ __launch_bounds__(512) void attn_fused(const short* __restrict__ qkv,
                                                  const short* __restrict__ vt,
                                                  float* __restrict__ wout,
                                                  short* __restrict__ merged) {
  __shared__ short smem[40960];              // 80 KB -> 2 blocks/CU
  short* const lW    = smem;                 // 128x64 bf16 = 8192 shorts
  short* const tiles = smem + 8192;          // 8 tile buffers x 4096 shorts
#define TB(i) (tiles + (i) * 4096)

  const int tid = threadIdx.x, lane = tid & 63, wid = tid >> 6;   // wid 0..7
  const int bh = blockIdx.y;
  const int qt = (blockIdx.y < 16) ? (15 - blockIdx.x) : blockIdx.x;
  const int b = bh >> 4, h = bh & 15;
  const int npairs = qt + 1;                 // NT/2; NT = 2*qt+2 k-tiles

  const int srow = tid >> 3;                        // 0..63 (staging row)
  const int scol = ((tid & 7) ^ (srow & 7)) * 8;    // pre-swizzled global col
  const int q15  = lane & 15;
  const int fcs  = (lane >> 4) * 8;                 // d-chunk within 32
  const int kg4  = (lane >> 4) << 2;                // k sub-offset within 16
  const int qg   = wid * 16 + q15;                  // q row in block (S/PV/lW)
  const int qglob = qt * 128 + qg;                  // global q row
  const int sw   = (q15 & 7) << 3;                  // lW/lK row swizzle
  const int qsub = (lane >> 4) << 2;
  const int qrow = qt * 128 + wid * 16 + qsub;      // O-rows (merged write)
  const int wave_qmin = qt * 128 + wid * 16;

  const short* ksrc0 = qkv + (size_t)(b * TT) * TQKV + EMB + h * HD;
  const short* vsrc0 = vt + (size_t)bh * HD * TT;

#define STAGE_K(dst, kt)                                                       \
  gload_lds16(ksrc0 + (size_t)((kt) * 64 + srow) * TQKV + scol, (dst) + tid * 8)
#define STAGE_V(dst, kt)                                                       \
  gload_lds16(vsrc0 + (size_t)srow * TT + (kt) * 64 + scol,     (dst) + tid * 8)

  // 1. stage Q (128 rows) into the lW slot, build Q-fragments
  const short* qsrc = qkv + ((size_t)(b * TT + qt * 128)) * TQKV + h * HD;
  gload_lds16(qsrc + (size_t)srow * TQKV + scol,        lW + tid * 8);
  gload_lds16(qsrc + (size_t)(srow + 64) * TQKV + scol, lW + 4096 + tid * 8);
  __syncthreads();

  s16x8 aq[2];
  aq[0] = *(const s16x8*)(lW + qg * 64 + ((fcs)      ^ ((qg & 7) << 3)));
  aq[1] = *(const s16x8*)(lW + qg * 64 + ((32 + fcs) ^ ((qg & 7) << 3)));

  // QK^T for one tile from buffer Kb (swapped operands)
#define QK_TILE(s2v, Kb)                                                       \
  do {                                                                         \
    _Pragma("unroll")                                                          \
    for (int kg = 0; kg < 4; ++kg) s2v[kg] = (f32x4){0.f, 0.f, 0.f, 0.f};      \
    __builtin_amdgcn_s_setprio(1);                                             \
    _Pragma("unroll")                                                          \
    for (int ks2 = 0; ks2 < 2; ++ks2)                                          \
      _Pragma("unroll")                                                        \
      for (int kg = 0; kg < 4; ++kg) {                                         \
        s16x8 bk = *(const s16x8*)((Kb) + (kg * 16 + q15) * 64 +               \
                                   ((ks2 * 32 + fcs) ^ sw));                   \
        s2v[kg] = __builtin_amdgcn_mfma_f32_16x16x32_bf16(bk, aq[ks2],         \
                                                          s2v[kg], 0, 0, 0);   \
      }                                                                        \
    __builtin_amdgcn_s_setprio(0);                                             \
  } while (0)

  // 2. phase 1: softmax denominator + interleaved zero-fill of the
  // strictly-upper w region. 2 QK-tiles per barrier; zero-chunk at
  // iteration start (oldest in FIFO -> forced by trailing vmcnt after a
  // full body of latency; prefetch gloads stay the 2 newest).
  float lsum = 0.f;
  {
    const int ZT = 32 - 2 * npairs;            // zero k-tiles (30-2qt)
    const int zchunk = (ZT + npairs - 1) / npairs;
    const int zr = tid >> 2, zc = (tid & 3) * 16;
    float* const zbase = wout + ((size_t)bh * TT + qt * 128 + zr) * TT + zc;
    const f32x4 zz = (f32x4){0.f, 0.f, 0.f, 0.f};

    STAGE_K(TB(0), 0); STAGE_K(TB(1), 1);
    if (npairs > 1) { STAGE_K(TB(2), 2); STAGE_K(TB(3), 3); }
    if (npairs > 1) bar_vm2(); else bar_vm0();
    for (int p = 0; p < npairs; ++p) {
      // zero-fill chunk first (oldest VMEM at this iter's trailing barrier)
      {
        const int z1 = (p + 1) * zchunk < ZT ? (p + 1) * zchunk : ZT;
        for (int z = p * zchunk; z < z1; ++z) {
          float* zp = zbase + (2 * npairs + z) * 64;
          *(f32x4*)(zp)      = zz;
          *(f32x4*)(zp + 4)  = zz;
          *(f32x4*)(zp + 8)  = zz;
          *(f32x4*)(zp + 12) = zz;
        }
      }
      const int s = p & 3;
      const bool pre = (p + 2 < npairs);
      if (pre) {
        const int sn = (p + 2) & 3;
        STAGE_K(TB(2 * sn),     2 * p + 4);
        STAGE_K(TB(2 * sn + 1), 2 * p + 5);
      }
      __builtin_amdgcn_sched_barrier(0);
#pragma unroll
      for (int u = 0; u < 2; ++u) {
        const int t = 2 * p + u;
        const short* Kb = TB(2 * s + u);
        f32x4 s2v[4];
        QK_TILE(s2v, Kb);
        const bool full = (t * 64 + 63 <= wave_qmin);
        const int kb0 = t * 64 + kg4;
#pragma unroll
        for (int kg = 0; kg < 4; ++kg)
#pragma unroll
          for (int r = 0; r < 4; ++r) {
            float e = exp2f(s2v[kg][r] * C_EXP2);
            if (!full) e = (kb0 + kg * 16 + r <= qglob) ? e : 0.f;
            lsum += e;
          }
      }
      if (p + 1 < npairs) { if (pre) bar_vm2(); else bar_vm0(); }
    }
  }
  lsum += __shfl_xor(lsum, 16);
  lsum += __shfl_xor(lsum, 32);
  const float lrl = -log2f(lsum);        // log2(1/l)

  // 3. phase 2: scores -> w (direct f32x4) -> P(lW) -> PV; 2 tiles/barrier.
  f32x4 o[4];
#pragma unroll
  for (int nj = 0; nj < 4; ++nj) o[nj] = (f32x4){0.f, 0.f, 0.f, 0.f};

  __syncthreads();                        // phase-1 LDS reads fully done
  {
    STAGE_K(TB(0), 0); STAGE_V(TB(1), 0); STAGE_K(TB(2), 1); STAGE_V(TB(3), 1);
    if (npairs > 1) {
      STAGE_K(TB(4), 2); STAGE_V(TB(5), 2); STAGE_K(TB(6), 3); STAGE_V(TB(7), 3);
    }
    if (npairs > 1) bar_vm4(); else bar_vm0();

    float* const wq_base = wout + ((size_t)bh * TT + qglob) * TT;

#define W_PV_TILE(s2v, t, Vb)                                                  \
  do {                                                                         \
    const bool full = ((t) * 64 + 63 <= wave_qmin);                            \
    float* wbase = wq_base + (t) * 64 + kg4;                                   \
    _Pragma("unroll")                                                          \
    for (int kg = 0; kg < 4; ++kg) {                                           \
      f32x4 w4;                                                                \
      _Pragma("unroll")                                                        \
      for (int r = 0; r < 4; ++r) {                                            \
        float e = exp2f(fmaf(s2v[kg][r], C_EXP2, lrl));                        \
        w4[r] = (full || ((t) * 64 + kg * 16 + kg4 + r <= qglob)) ? e : 0.f;   \
      }                                                                        \
      *(f32x4*)(wbase + kg * 16) = w4;                                         \
      u32x2 pk2;                                                               \
      pk2.x = cvt_pk_bf16(w4[0], w4[1]);                                       \
      pk2.y = cvt_pk_bf16(w4[2], w4[3]);                                       \
      const int col = kg * 16 + kg4;                                           \
      *(u32x2*)(lW + qg * 64 + (col ^ sw)) = pk2;                              \
    }                                                                          \
    __builtin_amdgcn_s_setprio(1);                                             \
    _Pragma("unroll")                                                          \
    for (int ks2 = 0; ks2 < 2; ++ks2) {                                        \
      s16x8 aw = *(const s16x8*)(lW + qg * 64 +                                \
                                 ((ks2 * 32 + fcs) ^ ((qg & 7) << 3)));        \
      _Pragma("unroll")                                                        \
      for (int nj = 0; nj < 4; ++nj) {                                         \
        s16x8 bv = *(const s16x8*)((Vb) + (nj * 16 + q15) * 64 +               \
                                   ((ks2 * 32 + fcs) ^ sw));                   \
        o[nj] = __builtin_amdgcn_mfma_f32_16x16x32_bf16(aw, bv, o[nj],         \
                                                        0, 0, 0);              \
      }                                                                        \
    }                                                                          \
    __builtin_amdgcn_s_setprio(0);                                             \
  } while (0)

    for (int p = 0; p < npairs; ++p) {
      const int s = p & 1;
      // tile t0 = 2p: QK first (reads slot s K)
      f32x4 s2v[4];
      QK_TILE(s2v, TB(4 * s));

      // stage pair p+1 into slot (p+1)&1 for p>=1 (pair 1 staged in prologue)
      const bool st = (p >= 1 && p + 1 < npairs);
      if (st) {
        const int sn = (p + 1) & 1;
        STAGE_K(TB(4 * sn),     2 * p + 2); STAGE_V(TB(4 * sn + 1), 2 * p + 2);
        STAGE_K(TB(4 * sn + 2), 2 * p + 3); STAGE_V(TB(4 * sn + 3), 2 * p + 3);
      }
      __builtin_amdgcn_sched_barrier(0);   // pin: gloads issue before w-stores

      W_PV_TILE(s2v, 2 * p, TB(4 * s + 1));

      // tile t1 = 2p+1
      QK_TILE(s2v, TB(4 * s + 2));
      W_PV_TILE(s2v, 2 * p + 1, TB(4 * s + 3));

      // trailing barrier: 8 newest VMEM = this pair's w-stores; everything
      // older (next pair's 4 gloads + old stores) is forced complete.
      if (p + 1 < npairs) bar_vm8();
    }
#undef W_PV_TILE
  }
#undef QK_TILE
#undef STAGE_K
#undef STAGE_V
#undef TB

  // 4. merged context [B*T, EMB] bf16
#pragma unroll
  for (int nj = 0; nj < 4; ++nj)
#pragma unroll
    for (int r = 0; r < 4; ++r)
      merged[(size_t)(b * TT + qrow + r) * EMB + h * HD + nj * 16 + q15] = f2bf(o[nj][r]);
}

// ---------- host launcher ----------
extern "C" void kernel_launch(void* const* d_in, const int* in_sizes, int n_in,
                              void* d_out, int out_size, void* d_ws, size_t ws_size,
                              hipStream_t stream) {
  const float* x  = (const float*)d_in[0];
  const float* WQ = (const float*)d_in[2];
  const float* WK = (const float*)d_in[3];
  const float* WV = (const float*)d_in[4];
  const float* WO = (const float*)d_in[5];

  float* y    = (float*)d_out;                          // [B,T,E]
  float* wout = (float*)d_out + (size_t)NB * TT * EMB;  // [B,H,T,T]

  char* ws = (char*)d_ws;
  short* xb     = (short*)(ws + 0);          //  8,388,608 B
  short* wqkv   = (short*)(ws + 8388608);    //  6,291,456 B
  short* wob    = (short*)(ws + 14680064);   //  2,097,152 B
  short* qkvb   = (short*)(ws + 16777216);   // 25,165,824 B
  short* vtb    = (short*)(ws + 41943040);   //  8,388,608 B
  short* merged = (short*)(ws + 50331648);   //  8,388,608 B

  // 1. all fp32 -> bf16 conversions, one launch
  cvt_all<<<8192, 256, 0, stream>>>(x, WQ, WK, WV, WO, xb, wqkv, wob);

  // 2. packed QKV projection (8-wave blocks, 3-buffer ring)
  gemm_nt<1><<<dim3(24, 32), 512, 0, stream>>>(xb, wqkv, qkvb, 4096, 3072, 1024);

  // 3. V transpose
  transpose_v<<<dim3(32, 32), 256, 0, stream>>>(qkvb, vtb);

  // 4. fused attention (QBLK=128, CU-balanced, swapped QK^T, pair-processed,
  //    zero-fill interleaved into phase 1)
  attn_fused<<<dim3(16, 32), 512, 0, stream>>>(qkvb, vtb, wout, merged);

  // 5. output projection (8-wave blocks, 3-buffer ring)
  gemm_nt<0><<<dim3(8, 32), 512, 0, stream>>>(merged, wob, y, 4096, 1024, 1024);
}

// Round 16
// 239.239 us; speedup vs baseline: 1.1397x; 1.1397x over previous
//
#include <hip/hip_runtime.h>
#include <cstdint>
#include <cstddef>

typedef __attribute__((ext_vector_type(4))) float  f32x4;
typedef __attribute__((ext_vector_type(8))) short  s16x8;
typedef __attribute__((ext_vector_type(4))) short  s16x4;
typedef __attribute__((ext_vector_type(2))) unsigned int u32x2;

#define EMB   1024
#define NHEAD 16
#define HD    64
#define NB    2
#define TT    2048
#define TQKV  3072   // packed Q|K|V column count

// exp(x*0.125) == exp2(x*0.18033688)
#define C_EXP2 0.18033688011112042f

// ---------- helpers ----------
__device__ __forceinline__ short f2bf(float f) {
  union { float f; unsigned u; } x; x.f = f;
  unsigned r = x.u + 0x7FFFu + ((x.u >> 16) & 1u);
  return (short)(r >> 16);
}

__device__ __forceinline__ unsigned cvt_pk_bf16(float lo, float hi) {
  unsigned r;
  asm("v_cvt_pk_bf16_f32 %0, %1, %2" : "=v"(r) : "v"(lo), "v"(hi));
  return r;
}

__device__ __forceinline__ void gload_lds16(const short* g, short* l) {
  __builtin_amdgcn_global_load_lds(
      (const __attribute__((address_space(1))) void*)(g),
      (__attribute__((address_space(3))) void*)(l), 16, 0, 0);
}

// counted-waitcnt barriers (T4): never drain stores to 0 in the hot loop.
// Lesson r15: stores issued BEFORE the counted wait are OLDER in the FIFO
// and get forced by it — only stores issued after the last counted wait
// stay in flight. Keep stores the newest ops before a counted barrier.
#define MAKE_BAR(NAME, N)                                          \
  __device__ __forceinline__ void NAME() {                         \
    asm volatile("s_waitcnt vmcnt(" #N ")" ::: "memory");          \
    __builtin_amdgcn_sched_barrier(0);                             \
    __builtin_amdgcn_s_barrier();                                  \
    __builtin_amdgcn_sched_barrier(0);                             \
  }
MAKE_BAR(bar_vm0, 0)
MAKE_BAR(bar_vm2, 2)
MAKE_BAR(bar_vm4, 4)
MAKE_BAR(bar_vm8, 8)
#undef MAKE_BAR

// bijective XCD swizzle (m204): nwg % 8 == 0 cases only
__device__ __forceinline__ int xcd_swz(int lin, int nwg) {
  const int chunk = nwg >> 3;
  return (lin & 7) * chunk + (lin >> 3);
}

// ---------- fp32 -> bf16 convert, all inputs in one launch ----------
__global__ __launch_bounds__(256) void cvt_all(
    const float* __restrict__ x,  const float* __restrict__ wq,
    const float* __restrict__ wk, const float* __restrict__ wv,
    const float* __restrict__ wo,
    short* __restrict__ xb, short* __restrict__ wqkv, short* __restrict__ wob) {
  int i = blockIdx.x * 256 + threadIdx.x;   // quad index, 2097152 total
  const float* s; short* d; int off;
  if (i < 1048576) { s = x; d = xb; off = i; }
  else {
    int j = i - 1048576;
    int r = j >> 18;            // 0..3
    off = j & 262143;
    s = (r == 0) ? wq : (r == 1) ? wk : (r == 2) ? wv : wo;
    d = (r == 3) ? wob : wqkv + (size_t)r * 1048576;
  }
  f32x4 v = ((const f32x4*)s)[off];
  s16x4 o;
  o[0] = f2bf(v[0]); o[1] = f2bf(v[1]); o[2] = f2bf(v[2]); o[3] = f2bf(v[3]);
  ((s16x4*)d)[off] = o;
}

// ---------- GEMM  C[M,N] = A[M,K] @ B[N,K]^T  (bf16 in, f32 acc) ----------
// 128x128 tile, BK=32, 8 waves (2x4), per-wave 64x32 (4x2 frags).
// Double-buffered staging (1 barrier/K-step, r13's measured-best form);
// XCD-aware bijective block swizzle (T1) for L2 panel locality.
template <int OUT_BF16>
__global__ __launch_bounds__(512) void gemm_nt(const short* __restrict__ A,
                                               const short* __restrict__ B,
                                               void* __restrict__ C,
                                               int M, int N, int K) {
  __shared__ short lA[2][128 * 32];
  __shared__ short lB[2][128 * 32];
  const int tid  = threadIdx.x;
  const int lane = tid & 63;
  const int wid  = tid >> 6;                 // 0..7
  const int nbn = N >> 7;
  const int lin = xcd_swz(blockIdx.x + nbn * blockIdx.y, nbn * (M >> 7));
  const int bn = lin % nbn, bm = lin / nbn;
  const int wm = wid >> 2, wn = wid & 3;     // 2 x 4 wave grid

  f32x4 acc[4][2];
#pragma unroll
  for (int i = 0; i < 4; ++i)
#pragma unroll
    for (int j = 0; j < 2; ++j) acc[i][j] = (f32x4){0.f, 0.f, 0.f, 0.f};

  const short* Ab = A + (size_t)bm * 128 * K;
  const short* Bb = B + (size_t)bn * 128 * K;
  const int srow = tid >> 2;                       // 0..127
  const int scol = (((tid & 3) ^ (srow & 3))) * 8; // pre-swizzled source group

#define G_STAGE(buf, k0)                                                     \
  do {                                                                       \
    gload_lds16(Ab + (size_t)srow * K + (k0) + scol, &lA[buf][tid * 8]);     \
    gload_lds16(Bb + (size_t)srow * K + (k0) + scol, &lB[buf][tid * 8]);     \
  } while (0)

  G_STAGE(0, 0);
  int cur = 0;
  for (int k0 = 0; k0 < K; k0 += 32) {
    __syncthreads();                 // cur buffer staged; prev reads drained
    if (k0 + 32 < K) G_STAGE(cur ^ 1, k0 + 32);

    s16x8 af[4], bf_[2];
#pragma unroll
    for (int i = 0; i < 4; ++i) {
      const int ra = wm * 64 + i * 16 + (lane & 15);
      af[i] = *(const s16x8*)(&lA[cur][ra * 32 + (((lane >> 4) ^ (ra & 3)) << 3)]);
    }
#pragma unroll
    for (int j = 0; j < 2; ++j) {
      const int rb = wn * 32 + j * 16 + (lane & 15);
      bf_[j] = *(const s16x8*)(&lB[cur][rb * 32 + (((lane >> 4) ^ (rb & 3)) << 3)]);
    }
#pragma unroll
    for (int i = 0; i < 4; ++i)
#pragma unroll
      for (int j = 0; j < 2; ++j)
        acc[i][j] = __builtin_amdgcn_mfma_f32_16x16x32_bf16(af[i], bf_[j], acc[i][j], 0, 0, 0);
    cur ^= 1;
  }
#undef G_STAGE

  const int row0 = bm * 128 + wm * 64;
  const int col0 = bn * 128 + wn * 32;
#pragma unroll
  for (int i = 0; i < 4; ++i)
#pragma unroll
    for (int j = 0; j < 2; ++j)
#pragma unroll
      for (int r = 0; r < 4; ++r) {
        int row = row0 + i * 16 + ((lane >> 4) << 2) + r;
        int col = col0 + j * 16 + (lane & 15);
        float v = acc[i][j][r];
        if (OUT_BF16) ((short*)C)[(size_t)row * N + col] = f2bf(v);
        else          ((float*)C)[(size_t)row * N + col] = v;
      }
}

// ---------- V transpose: Vt[bh][d][t] ----------
__global__ __launch_bounds__(256) void transpose_v(const short* __restrict__ qkv,
                                                   short* __restrict__ vt) {
  __shared__ short tile[64 * 72];
  const int tt = blockIdx.x, bh = blockIdx.y;
  const int b = bh >> 4, h = bh & 15;
  const int tid = threadIdx.x;

  const short* src = qkv + ((size_t)(b * TT + tt * 64)) * TQKV + 2048 + h * HD;
#pragma unroll
  for (int p = 0; p < 2; ++p) {
    int r = p * 32 + (tid >> 3);
    int c = (tid & 7) * 8;
    s16x8 v = *(const s16x8*)(src + (size_t)r * TQKV + c);
#pragma unroll
    for (int j = 0; j < 8; ++j) tile[r * 72 + c + j] = v[j];
  }
  __syncthreads();
  short* dst = vt + ((size_t)bh * HD) * TT + tt * 64;
#pragma unroll
  for (int p = 0; p < 2; ++p) {
    int d0 = p * 32 + (tid >> 3);
    int c  = (tid & 7) * 8;
    s16x8 o;
#pragma unroll
    for (int j = 0; j < 8; ++j) o[j] = tile[(c + j) * 72 + d0];
    *(s16x8*)(dst + (size_t)d0 * TT + c) = o;
  }
}

// ---------- fused attention: QBLK=128, 8 waves, swapped QK^T, pairs -------
// (exact r13 structure, the measured-best 239.5us version)
__global__ __launch_bounds__(512) void attn_fused(const short* __restrict__ qkv,
                                                  const short* __restrict__ vt,
                                                  float* __restrict__ wout,
                                                  short* __restrict__ merged) {
  __shared__ short smem[40960];              // 80 KB -> 2 blocks/CU
  short* const lW    = smem;                 // 128x64 bf16 = 8192 shorts
  short* const tiles = smem + 8192;          // 8 tile buffers x 4096 shorts
#define TB(i) (tiles + (i) * 4096)

  const int tid = threadIdx.x, lane = tid & 63, wid = tid >> 6;   // wid 0..7
  const int bh = blockIdx.y;
  const int qt = (blockIdx.y < 16) ? (15 - blockIdx.x) : blockIdx.x;
  const int b = bh >> 4, h = bh & 15;
  const int npairs = qt + 1;                 // NT/2; NT = 2*qt+2 k-tiles

  const int srow = tid >> 3;                        // 0..63 (staging row)
  const int scol = ((tid & 7) ^ (srow & 7)) * 8;    // pre-swizzled global col
  const int q15  = lane & 15;
  const int fcs  = (lane >> 4) * 8;                 // d-chunk within 32
  const int kg4  = (lane >> 4) << 2;                // k sub-offset within 16
  const int qg   = wid * 16 + q15;                  // q row in block (S/PV/lW)
  const int qglob = qt * 128 + qg;                  // global q row
  const int sw   = (q15 & 7) << 3;                  // lW/lK row swizzle
  const int qsub = (lane >> 4) << 2;
  const int qrow = qt * 128 + wid * 16 + qsub;      // O-rows (merged write)
  const int wave_qmin = qt * 128 + wid * 16;

  const short* ksrc0 = qkv + (size_t)(b * TT) * TQKV + EMB + h * HD;
  const short* vsrc0 = vt + (size_t)bh * HD * TT;

#define STAGE_K(dst, kt)                                                       \
  gload_lds16(ksrc0 + (size_t)((kt) * 64 + srow) * TQKV + scol, (dst) + tid * 8)
#define STAGE_V(dst, kt)                                                       \
  gload_lds16(vsrc0 + (size_t)srow * TT + (kt) * 64 + scol,     (dst) + tid * 8)

  // 1. stage Q (128 rows) into the lW slot, build Q-fragments
  const short* qsrc = qkv + ((size_t)(b * TT + qt * 128)) * TQKV + h * HD;
  gload_lds16(qsrc + (size_t)srow * TQKV + scol,        lW + tid * 8);
  gload_lds16(qsrc + (size_t)(srow + 64) * TQKV + scol, lW + 4096 + tid * 8);
  __syncthreads();

  s16x8 aq[2];
  aq[0] = *(const s16x8*)(lW + qg * 64 + ((fcs)      ^ ((qg & 7) << 3)));
  aq[1] = *(const s16x8*)(lW + qg * 64 + ((32 + fcs) ^ ((qg & 7) << 3)));

  // QK^T for one tile from buffer Kb (swapped operands)
#define QK_TILE(s2v, Kb)                                                       \
  do {                                                                         \
    _Pragma("unroll")                                                          \
    for (int kg = 0; kg < 4; ++kg) s2v[kg] = (f32x4){0.f, 0.f, 0.f, 0.f};      \
    __builtin_amdgcn_s_setprio(1);                                             \
    _Pragma("unroll")                                                          \
    for (int ks2 = 0; ks2 < 2; ++ks2)                                          \
      _Pragma("unroll")                                                        \
      for (int kg = 0; kg < 4; ++kg) {                                         \
        s16x8 bk = *(const s16x8*)((Kb) + (kg * 16 + q15) * 64 +               \
                                   ((ks2 * 32 + fcs) ^ sw));                   \
        s2v[kg] = __builtin_amdgcn_mfma_f32_16x16x32_bf16(bk, aq[ks2],         \
                                                          s2v[kg], 0, 0, 0);   \
      }                                                                        \
    __builtin_amdgcn_s_setprio(0);                                             \
  } while (0)

  // 2. phase 1: softmax denominator (one scalar/lane); 2 tiles per barrier.
  float lsum = 0.f;
  {
    STAGE_K(TB(0), 0); STAGE_K(TB(1), 1);
    if (npairs > 1) { STAGE_K(TB(2), 2); STAGE_K(TB(3), 3); }
    if (npairs > 1) bar_vm2(); else bar_vm0();
    for (int p = 0; p < npairs; ++p) {
      const int s = p & 3;
      const bool pre = (p + 2 < npairs);
      if (pre) {
        const int sn = (p + 2) & 3;
        STAGE_K(TB(2 * sn),     2 * p + 4);
        STAGE_K(TB(2 * sn + 1), 2 * p + 5);
      }
      __builtin_amdgcn_sched_barrier(0);
#pragma unroll
      for (int u = 0; u < 2; ++u) {
        const int t = 2 * p + u;
        const short* Kb = TB(2 * s + u);
        f32x4 s2v[4];
        QK_TILE(s2v, Kb);
        const bool full = (t * 64 + 63 <= wave_qmin);
        const int kb0 = t * 64 + kg4;
#pragma unroll
        for (int kg = 0; kg < 4; ++kg)
#pragma unroll
          for (int r = 0; r < 4; ++r) {
            float e = exp2f(s2v[kg][r] * C_EXP2);
            if (!full) e = (kb0 + kg * 16 + r <= qglob) ? e : 0.f;
            lsum += e;
          }
      }
      if (p + 1 < npairs) { if (pre) bar_vm2(); else bar_vm0(); }
    }
  }
  lsum += __shfl_xor(lsum, 16);
  lsum += __shfl_xor(lsum, 32);
  const float lrl = -log2f(lsum);        // log2(1/l)

  // 3. phase 2: scores -> w (direct f32x4) -> P(lW) -> PV; 2 tiles/barrier.
  f32x4 o[4];
#pragma unroll
  for (int nj = 0; nj < 4; ++nj) o[nj] = (f32x4){0.f, 0.f, 0.f, 0.f};

  __syncthreads();                        // phase-1 LDS reads fully done
  {
    STAGE_K(TB(0), 0); STAGE_V(TB(1), 0); STAGE_K(TB(2), 1); STAGE_V(TB(3), 1);
    if (npairs > 1) {
      STAGE_K(TB(4), 2); STAGE_V(TB(5), 2); STAGE_K(TB(6), 3); STAGE_V(TB(7), 3);
    }
    if (npairs > 1) bar_vm4(); else bar_vm0();

    float* const wq_base = wout + ((size_t)bh * TT + qglob) * TT;

#define W_PV_TILE(s2v, t, Vb)                                                  \
  do {                                                                         \
    const bool full = ((t) * 64 + 63 <= wave_qmin);                            \
    float* wbase = wq_base + (t) * 64 + kg4;                                   \
    _Pragma("unroll")                                                          \
    for (int kg = 0; kg < 4; ++kg) {                                           \
      f32x4 w4;                                                                \
      _Pragma("unroll")                                                        \
      for (int r = 0; r < 4; ++r) {                                            \
        float e = exp2f(fmaf(s2v[kg][r], C_EXP2, lrl));                        \
        w4[r] = (full || ((t) * 64 + kg * 16 + kg4 + r <= qglob)) ? e : 0.f;   \
      }                                                                        \
      *(f32x4*)(wbase + kg * 16) = w4;                                         \
      u32x2 pk2;                                                               \
      pk2.x = cvt_pk_bf16(w4[0], w4[1]);                                       \
      pk2.y = cvt_pk_bf16(w4[2], w4[3]);                                       \
      const int col = kg * 16 + kg4;                                           \
      *(u32x2*)(lW + qg * 64 + (col ^ sw)) = pk2;                              \
    }                                                                          \
    __builtin_amdgcn_s_setprio(1);                                             \
    _Pragma("unroll")                                                          \
    for (int ks2 = 0; ks2 < 2; ++ks2) {                                        \
      s16x8 aw = *(const s16x8*)(lW + qg * 64 +                                \
                                 ((ks2 * 32 + fcs) ^ ((qg & 7) << 3)));        \
      _Pragma("unroll")                                                        \
      for (int nj = 0; nj < 4; ++nj) {                                         \
        s16x8 bv = *(const s16x8*)((Vb) + (nj * 16 + q15) * 64 +               \
                                   ((ks2 * 32 + fcs) ^ sw));                   \
        o[nj] = __builtin_amdgcn_mfma_f32_16x16x32_bf16(aw, bv, o[nj],         \
                                                        0, 0, 0);              \
      }                                                                        \
    }                                                                          \
    __builtin_amdgcn_s_setprio(0);                                             \
  } while (0)

    for (int p = 0; p < npairs; ++p) {
      const int s = p & 1;
      // tile t0 = 2p: QK first (reads slot s K)
      f32x4 s2v[4];
      QK_TILE(s2v, TB(4 * s));

      // stage pair p+1 into slot (p+1)&1 for p>=1 (pair 1 staged in prologue)
      const bool st = (p >= 1 && p + 1 < npairs);
      if (st) {
        const int sn = (p + 1) & 1;
        STAGE_K(TB(4 * sn),     2 * p + 2); STAGE_V(TB(4 * sn + 1), 2 * p + 2);
        STAGE_K(TB(4 * sn + 2), 2 * p + 3); STAGE_V(TB(4 * sn + 3), 2 * p + 3);
      }
      __builtin_amdgcn_sched_barrier(0);   // pin: gloads issue before w-stores

      W_PV_TILE(s2v, 2 * p, TB(4 * s + 1));

      // tile t1 = 2p+1
      QK_TILE(s2v, TB(4 * s + 2));
      W_PV_TILE(s2v, 2 * p + 1, TB(4 * s + 3));

      // trailing barrier: 8 newest VMEM = this pair's w-stores; everything
      // older (next pair's 4 gloads + old stores) is forced complete.
      if (p + 1 < npairs) bar_vm8();
    }
#undef W_PV_TILE
  }
#undef QK_TILE
#undef STAGE_K
#undef STAGE_V
#undef TB

  // 4. merged context [B*T, EMB] bf16
#pragma unroll
  for (int nj = 0; nj < 4; ++nj)
#pragma unroll
    for (int r = 0; r < 4; ++r)
      merged[(size_t)(b * TT + qrow + r) * EMB + h * HD + nj * 16 + q15] = f2bf(o[nj][r]);

  // 5. zero strictly-upper tiles (drains at kernel end — no barrier after,
  //    so these stores never feed a vmcnt drain; r15's in-loop variant
  //    regressed 33us by violating exactly that)
  {
    const int zrow = tid >> 2, zc = (tid & 3) * 16;
    float* zbase = wout + ((size_t)bh * TT + qt * 128 + zrow) * TT + zc;
    const f32x4 z = (f32x4){0.f, 0.f, 0.f, 0.f};
    for (int kt = 2 * qt + 2; kt < TT / 64; ++kt) {
      float* p = zbase + kt * 64;
      *(f32x4*)(p)      = z;
      *(f32x4*)(p + 4)  = z;
      *(f32x4*)(p + 8)  = z;
      *(f32x4*)(p + 12) = z;
    }
  }
}

// ---------- host launcher ----------
extern "C" void kernel_launch(void* const* d_in, const int* in_sizes, int n_in,
                              void* d_out, int out_size, void* d_ws, size_t ws_size,
                              hipStream_t stream) {
  const float* x  = (const float*)d_in[0];
  const float* WQ = (const float*)d_in[2];
  const float* WK = (const float*)d_in[3];
  const float* WV = (const float*)d_in[4];
  const float* WO = (const float*)d_in[5];

  float* y    = (float*)d_out;                          // [B,T,E]
  float* wout = (float*)d_out + (size_t)NB * TT * EMB;  // [B,H,T,T]

  char* ws = (char*)d_ws;
  short* xb     = (short*)(ws + 0);          //  8,388,608 B
  short* wqkv   = (short*)(ws + 8388608);    //  6,291,456 B
  short* wob    = (short*)(ws + 14680064);   //  2,097,152 B
  short* qkvb   = (short*)(ws + 16777216);   // 25,165,824 B
  short* vtb    = (short*)(ws + 41943040);   //  8,388,608 B
  short* merged = (short*)(ws + 50331648);   //  8,388,608 B

  // 1. all fp32 -> bf16 conversions, one launch
  cvt_all<<<8192, 256, 0, stream>>>(x, WQ, WK, WV, WO, xb, wqkv, wob);

  // 2. packed QKV projection (8-wave blocks, XCD-swizzled)
  gemm_nt<1><<<dim3(24, 32), 512, 0, stream>>>(xb, wqkv, qkvb, 4096, 3072, 1024);

  // 3. V transpose
  transpose_v<<<dim3(32, 32), 256, 0, stream>>>(qkvb, vtb);

  // 4. fused attention (r13 structure: QBLK=128, CU-balanced, swapped QK^T,
  //    pair-processed, tail zero-fill)
  attn_fused<<<dim3(16, 32), 512, 0, stream>>>(qkvb, vtb, wout, merged);

  // 5. output projection (8-wave blocks, XCD-swizzled)
  gemm_nt<0><<<dim3(8, 32), 512, 0, stream>>>(merged, wob, y, 4096, 1024, 1024);
}

// Round 17
// 231.260 us; speedup vs baseline: 1.1790x; 1.0345x over previous
//
#include <hip/hip_runtime.h>
#include <cstdint>
#include <cstddef>

typedef __attribute__((ext_vector_type(4))) float  f32x4;
typedef __attribute__((ext_vector_type(8))) short  s16x8;
typedef __attribute__((ext_vector_type(4))) short  s16x4;
typedef __attribute__((ext_vector_type(2))) unsigned int u32x2;

#define EMB   1024
#define NHEAD 16
#define HD    64
#define NB    2
#define TT    2048
#define TQKV  3072   // packed Q|K|V column count

// exp(x*0.125) == exp2(x*0.18033688)
#define C_EXP2 0.18033688011112042f

// ---------- helpers ----------
__device__ __forceinline__ short f2bf(float f) {
  union { float f; unsigned u; } x; x.f = f;
  unsigned r = x.u + 0x7FFFu + ((x.u >> 16) & 1u);
  return (short)(r >> 16);
}

__device__ __forceinline__ unsigned cvt_pk_bf16(float lo, float hi) {
  unsigned r;
  asm("v_cvt_pk_bf16_f32 %0, %1, %2" : "=v"(r) : "v"(lo), "v"(hi));
  return r;
}

__device__ __forceinline__ void gload_lds16(const short* g, short* l) {
  __builtin_amdgcn_global_load_lds(
      (const __attribute__((address_space(1))) void*)(g),
      (__attribute__((address_space(3))) void*)(l), 16, 0, 0);
}

// counted-waitcnt barriers (T4): never drain stores to 0 in the hot loop.
// Lesson r15: stores issued BEFORE the counted wait are OLDER in the FIFO
// and get forced by it — keep stores the newest ops before a counted barrier.
#define MAKE_BAR(NAME, N)                                          \
  __device__ __forceinline__ void NAME() {                         \
    asm volatile("s_waitcnt vmcnt(" #N ")" ::: "memory");          \
    __builtin_amdgcn_sched_barrier(0);                             \
    __builtin_amdgcn_s_barrier();                                  \
    __builtin_amdgcn_sched_barrier(0);                             \
  }
MAKE_BAR(bar_vm0, 0)
MAKE_BAR(bar_vm2, 2)
MAKE_BAR(bar_vm4, 4)
MAKE_BAR(bar_vm8, 8)
#undef MAKE_BAR

// bijective XCD swizzle (m204): nwg % 8 == 0 cases only
__device__ __forceinline__ int xcd_swz(int lin, int nwg) {
  const int chunk = nwg >> 3;
  return (lin & 7) * chunk + (lin >> 3);
}

// ---------- fp32 -> bf16 convert, all inputs in one launch ----------
__global__ __launch_bounds__(256) void cvt_all(
    const float* __restrict__ x,  const float* __restrict__ wq,
    const float* __restrict__ wk, const float* __restrict__ wv,
    const float* __restrict__ wo,
    short* __restrict__ xb, short* __restrict__ wqkv, short* __restrict__ wob) {
  int i = blockIdx.x * 256 + threadIdx.x;   // quad index, 2097152 total
  const float* s; short* d; int off;
  if (i < 1048576) { s = x; d = xb; off = i; }
  else {
    int j = i - 1048576;
    int r = j >> 18;            // 0..3
    off = j & 262143;
    s = (r == 0) ? wq : (r == 1) ? wk : (r == 2) ? wv : wo;
    d = (r == 3) ? wob : wqkv + (size_t)r * 1048576;
  }
  f32x4 v = ((const f32x4*)s)[off];
  s16x4 o;
  o[0] = f2bf(v[0]); o[1] = f2bf(v[1]); o[2] = f2bf(v[2]); o[3] = f2bf(v[3]);
  ((s16x4*)d)[off] = o;
}

// ---------- GEMM  C[M,N] = A[M,K] @ B[N,K]^T  (bf16 in, f32 acc) ----------
// 128x128 tile, BK=32, 8 waves (2x4), per-wave 64x32 (4x2 frags),
// double-buffered staging, XCD swizzle.
// r17: for V-region blocks (VT != nullptr, bn >= 16) the epilogue routes the
// tile through an LDS transpose and writes Vt[bh][d][t] DIRECTLY — the
// transpose_v kernel and the qkvb V-region write are eliminated.
template <int OUT_BF16>
__global__ __launch_bounds__(512) void gemm_nt(const short* __restrict__ A,
                                               const short* __restrict__ B,
                                               void* __restrict__ C,
                                               short* __restrict__ VT,
                                               int M, int N, int K) {
  // union: staging (16384 shorts) / transpose tile [128][136] (17408 shorts)
  __shared__ short smem_u[17408];
  short* const lA0 = smem_u;
  short* const lA1 = smem_u + 4096;
  short* const lB0 = smem_u + 8192;
  short* const lB1 = smem_u + 12288;

  const int tid  = threadIdx.x;
  const int lane = tid & 63;
  const int wid  = tid >> 6;                 // 0..7
  const int nbn = N >> 7;
  const int lin = xcd_swz(blockIdx.x + nbn * blockIdx.y, nbn * (M >> 7));
  const int bn = lin % nbn, bm = lin / nbn;
  const int wm = wid >> 2, wn = wid & 3;     // 2 x 4 wave grid

  f32x4 acc[4][2];
#pragma unroll
  for (int i = 0; i < 4; ++i)
#pragma unroll
    for (int j = 0; j < 2; ++j) acc[i][j] = (f32x4){0.f, 0.f, 0.f, 0.f};

  const short* Ab = A + (size_t)bm * 128 * K;
  const short* Bb = B + (size_t)bn * 128 * K;
  const int srow = tid >> 2;                       // 0..127
  const int scol = (((tid & 3) ^ (srow & 3))) * 8; // pre-swizzled source group

#define G_STAGE(buf, k0)                                                       \
  do {                                                                         \
    gload_lds16(Ab + (size_t)srow * K + (k0) + scol,                           \
                ((buf) ? lA1 : lA0) + tid * 8);                                \
    gload_lds16(Bb + (size_t)srow * K + (k0) + scol,                           \
                ((buf) ? lB1 : lB0) + tid * 8);                                \
  } while (0)

  G_STAGE(0, 0);
  int cur = 0;
  for (int k0 = 0; k0 < K; k0 += 32) {
    __syncthreads();                 // cur buffer staged; prev reads drained
    if (k0 + 32 < K) G_STAGE(cur ^ 1, k0 + 32);

    const short* la = cur ? lA1 : lA0;
    const short* lb = cur ? lB1 : lB0;
    s16x8 af[4], bf_[2];
#pragma unroll
    for (int i = 0; i < 4; ++i) {
      const int ra = wm * 64 + i * 16 + (lane & 15);
      af[i] = *(const s16x8*)(la + ra * 32 + (((lane >> 4) ^ (ra & 3)) << 3));
    }
#pragma unroll
    for (int j = 0; j < 2; ++j) {
      const int rb = wn * 32 + j * 16 + (lane & 15);
      bf_[j] = *(const s16x8*)(lb + rb * 32 + (((lane >> 4) ^ (rb & 3)) << 3));
    }
#pragma unroll
    for (int i = 0; i < 4; ++i)
#pragma unroll
      for (int j = 0; j < 2; ++j)
        acc[i][j] = __builtin_amdgcn_mfma_f32_16x16x32_bf16(af[i], bf_[j], acc[i][j], 0, 0, 0);
    cur ^= 1;
  }
#undef G_STAGE

  if (OUT_BF16 && VT != nullptr && bn >= 16) {
    // ---- V block: transpose in LDS, write Vt[bh][d][t] ----
    __syncthreads();                       // all staging-LDS reads done
    short* const tile = smem_u;            // [128 cols][136] (d-major)
#pragma unroll
    for (int i = 0; i < 4; ++i)
#pragma unroll
      for (int j = 0; j < 2; ++j) {
        const int c    = wn * 32 + j * 16 + (lane & 15);          // col-local
        const int rloc = wm * 64 + i * 16 + ((lane >> 4) << 2);   // row-local
        s16x4 h4;
#pragma unroll
        for (int r = 0; r < 4; ++r) h4[r] = f2bf(acc[i][j][r]);
        *(s16x4*)(tile + c * 136 + rloc) = h4;
      }
    __syncthreads();
    const int b  = bm >> 4;
    const int h0 = 2 * bn - 32;            // first head in this block
    const int dl = tid >> 2;               // 0..127 (col-local = d-local)
    const int t0 = (tid & 3) * 32;
    const int h  = h0 + (dl >> 6), d = dl & 63;
    short* dst = VT + ((size_t)(b * NHEAD + h) * HD + d) * TT
                    + (bm & 15) * 128 + t0;
    const short* src = tile + dl * 136 + t0;
#pragma unroll
    for (int k = 0; k < 4; ++k)
      *(s16x8*)(dst + k * 8) = *(const s16x8*)(src + k * 8);
    return;
  }

  const int row0 = bm * 128 + wm * 64;
  const int col0 = bn * 128 + wn * 32;
#pragma unroll
  for (int i = 0; i < 4; ++i)
#pragma unroll
    for (int j = 0; j < 2; ++j)
#pragma unroll
      for (int r = 0; r < 4; ++r) {
        int row = row0 + i * 16 + ((lane >> 4) << 2) + r;
        int col = col0 + j * 16 + (lane & 15);
        float v = acc[i][j][r];
        if (OUT_BF16) ((short*)C)[(size_t)row * N + col] = f2bf(v);
        else          ((float*)C)[(size_t)row * N + col] = v;
      }
}

// ---------- fused attention: QBLK=128, 8 waves, swapped QK^T, pairs -------
// (exact r13/r16 structure, the measured-best version)
__global__ __launch_bounds__(512) void attn_fused(const short* __restrict__ qkv,
                                                  const short* __restrict__ vt,
                                                  float* __restrict__ wout,
                                                  short* __restrict__ merged) {
  __shared__ short smem[40960];              // 80 KB -> 2 blocks/CU
  short* const lW    = smem;                 // 128x64 bf16 = 8192 shorts
  short* const tiles = smem + 8192;          // 8 tile buffers x 4096 shorts
#define TB(i) (tiles + (i) * 4096)

  const int tid = threadIdx.x, lane = tid & 63, wid = tid >> 6;   // wid 0..7
  const int bh = blockIdx.y;
  const int qt = (blockIdx.y < 16) ? (15 - blockIdx.x) : blockIdx.x;
  const int b = bh >> 4, h = bh & 15;
  const int npairs = qt + 1;                 // NT/2; NT = 2*qt+2 k-tiles

  const int srow = tid >> 3;                        // 0..63 (staging row)
  const int scol = ((tid & 7) ^ (srow & 7)) * 8;    // pre-swizzled global col
  const int q15  = lane & 15;
  const int fcs  = (lane >> 4) * 8;                 // d-chunk within 32
  const int kg4  = (lane >> 4) << 2;                // k sub-offset within 16
  const int qg   = wid * 16 + q15;                  // q row in block (S/PV/lW)
  const int qglob = qt * 128 + qg;                  // global q row
  const int sw   = (q15 & 7) << 3;                  // lW/lK row swizzle
  const int qsub = (lane >> 4) << 2;
  const int qrow = qt * 128 + wid * 16 + qsub;      // O-rows (merged write)
  const int wave_qmin = qt * 128 + wid * 16;

  const short* ksrc0 = qkv + (size_t)(b * TT) * TQKV + EMB + h * HD;
  const short* vsrc0 = vt + (size_t)bh * HD * TT;

#define STAGE_K(dst, kt)                                                       \
  gload_lds16(ksrc0 + (size_t)((kt) * 64 + srow) * TQKV + scol, (dst) + tid * 8)
#define STAGE_V(dst, kt)                                                       \
  gload_lds16(vsrc0 + (size_t)srow * TT + (kt) * 64 + scol,     (dst) + tid * 8)

  // 1. stage Q (128 rows) into the lW slot, build Q-fragments
  const short* qsrc = qkv + ((size_t)(b * TT + qt * 128)) * TQKV + h * HD;
  gload_lds16(qsrc + (size_t)srow * TQKV + scol,        lW + tid * 8);
  gload_lds16(qsrc + (size_t)(srow + 64) * TQKV + scol, lW + 4096 + tid * 8);
  __syncthreads();

  s16x8 aq[2];
  aq[0] = *(const s16x8*)(lW + qg * 64 + ((fcs)      ^ ((qg & 7) << 3)));
  aq[1] = *(const s16x8*)(lW + qg * 64 + ((32 + fcs) ^ ((qg & 7) << 3)));

  // QK^T for one tile from buffer Kb (swapped operands)
#define QK_TILE(s2v, Kb)                                                       \
  do {                                                                         \
    _Pragma("unroll")                                                          \
    for (int kg = 0; kg < 4; ++kg) s2v[kg] = (f32x4){0.f, 0.f, 0.f, 0.f};      \
    __builtin_amdgcn_s_setprio(1);                                             \
    _Pragma("unroll")                                                          \
    for (int ks2 = 0; ks2 < 2; ++ks2)                                          \
      _Pragma("unroll")                                                        \
      for (int kg = 0; kg < 4; ++kg) {                                         \
        s16x8 bk = *(const s16x8*)((Kb) + (kg * 16 + q15) * 64 +               \
                                   ((ks2 * 32 + fcs) ^ sw));                   \
        s2v[kg] = __builtin_amdgcn_mfma_f32_16x16x32_bf16(bk, aq[ks2],         \
                                                          s2v[kg], 0, 0, 0);   \
      }                                                                        \
    __builtin_amdgcn_s_setprio(0);                                             \
  } while (0)

  // 2. phase 1: softmax denominator (one scalar/lane); 2 tiles per barrier.
  float lsum = 0.f;
  {
    STAGE_K(TB(0), 0); STAGE_K(TB(1), 1);
    if (npairs > 1) { STAGE_K(TB(2), 2); STAGE_K(TB(3), 3); }
    if (npairs > 1) bar_vm2(); else bar_vm0();
    for (int p = 0; p < npairs; ++p) {
      const int s = p & 3;
      const bool pre = (p + 2 < npairs);
      if (pre) {
        const int sn = (p + 2) & 3;
        STAGE_K(TB(2 * sn),     2 * p + 4);
        STAGE_K(TB(2 * sn + 1), 2 * p + 5);
      }
      __builtin_amdgcn_sched_barrier(0);
#pragma unroll
      for (int u = 0; u < 2; ++u) {
        const int t = 2 * p + u;
        const short* Kb = TB(2 * s + u);
        f32x4 s2v[4];
        QK_TILE(s2v, Kb);
        const bool full = (t * 64 + 63 <= wave_qmin);
        const int kb0 = t * 64 + kg4;
#pragma unroll
        for (int kg = 0; kg < 4; ++kg)
#pragma unroll
          for (int r = 0; r < 4; ++r) {
            float e = exp2f(s2v[kg][r] * C_EXP2);
            if (!full) e = (kb0 + kg * 16 + r <= qglob) ? e : 0.f;
            lsum += e;
          }
      }
      if (p + 1 < npairs) { if (pre) bar_vm2(); else bar_vm0(); }
    }
  }
  lsum += __shfl_xor(lsum, 16);
  lsum += __shfl_xor(lsum, 32);
  const float lrl = -log2f(lsum);        // log2(1/l)

  // 3. phase 2: scores -> w (direct f32x4) -> P(lW) -> PV; 2 tiles/barrier.
  f32x4 o[4];
#pragma unroll
  for (int nj = 0; nj < 4; ++nj) o[nj] = (f32x4){0.f, 0.f, 0.f, 0.f};

  __syncthreads();                        // phase-1 LDS reads fully done
  {
    STAGE_K(TB(0), 0); STAGE_V(TB(1), 0); STAGE_K(TB(2), 1); STAGE_V(TB(3), 1);
    if (npairs > 1) {
      STAGE_K(TB(4), 2); STAGE_V(TB(5), 2); STAGE_K(TB(6), 3); STAGE_V(TB(7), 3);
    }
    if (npairs > 1) bar_vm4(); else bar_vm0();

    float* const wq_base = wout + ((size_t)bh * TT + qglob) * TT;

#define W_PV_TILE(s2v, t, Vb)                                                  \
  do {                                                                         \
    const bool full = ((t) * 64 + 63 <= wave_qmin);                            \
    float* wbase = wq_base + (t) * 64 + kg4;                                   \
    _Pragma("unroll")                                                          \
    for (int kg = 0; kg < 4; ++kg) {                                           \
      f32x4 w4;                                                                \
      _Pragma("unroll")                                                        \
      for (int r = 0; r < 4; ++r) {                                            \
        float e = exp2f(fmaf(s2v[kg][r], C_EXP2, lrl));                        \
        w4[r] = (full || ((t) * 64 + kg * 16 + kg4 + r <= qglob)) ? e : 0.f;   \
      }                                                                        \
      *(f32x4*)(wbase + kg * 16) = w4;                                         \
      u32x2 pk2;                                                               \
      pk2.x = cvt_pk_bf16(w4[0], w4[1]);                                       \
      pk2.y = cvt_pk_bf16(w4[2], w4[3]);                                       \
      const int col = kg * 16 + kg4;                                           \
      *(u32x2*)(lW + qg * 64 + (col ^ sw)) = pk2;                              \
    }                                                                          \
    __builtin_amdgcn_s_setprio(1);                                             \
    _Pragma("unroll")                                                          \
    for (int ks2 = 0; ks2 < 2; ++ks2) {                                        \
      s16x8 aw = *(const s16x8*)(lW + qg * 64 +                                \
                                 ((ks2 * 32 + fcs) ^ ((qg & 7) << 3)));        \
      _Pragma("unroll")                                                        \
      for (int nj = 0; nj < 4; ++nj) {                                         \
        s16x8 bv = *(const s16x8*)((Vb) + (nj * 16 + q15) * 64 +               \
                                   ((ks2 * 32 + fcs) ^ sw));                   \
        o[nj] = __builtin_amdgcn_mfma_f32_16x16x32_bf16(aw, bv, o[nj],         \
                                                        0, 0, 0);              \
      }                                                                        \
    }                                                                          \
    __builtin_amdgcn_s_setprio(0);                                             \
  } while (0)

    for (int p = 0; p < npairs; ++p) {
      const int s = p & 1;
      // tile t0 = 2p: QK first (reads slot s K)
      f32x4 s2v[4];
      QK_TILE(s2v, TB(4 * s));

      // stage pair p+1 into slot (p+1)&1 for p>=1 (pair 1 staged in prologue)
      const bool st = (p >= 1 && p + 1 < npairs);
      if (st) {
        const int sn = (p + 1) & 1;
        STAGE_K(TB(4 * sn),     2 * p + 2); STAGE_V(TB(4 * sn + 1), 2 * p + 2);
        STAGE_K(TB(4 * sn + 2), 2 * p + 3); STAGE_V(TB(4 * sn + 3), 2 * p + 3);
      }
      __builtin_amdgcn_sched_barrier(0);   // pin: gloads issue before w-stores

      W_PV_TILE(s2v, 2 * p, TB(4 * s + 1));

      // tile t1 = 2p+1
      QK_TILE(s2v, TB(4 * s + 2));
      W_PV_TILE(s2v, 2 * p + 1, TB(4 * s + 3));

      // trailing barrier: 8 newest VMEM = this pair's w-stores; everything
      // older (next pair's 4 gloads + old stores) is forced complete.
      if (p + 1 < npairs) bar_vm8();
    }
#undef W_PV_TILE
  }
#undef QK_TILE
#undef STAGE_K
#undef STAGE_V
#undef TB

  // 4. merged context [B*T, EMB] bf16
#pragma unroll
  for (int nj = 0; nj < 4; ++nj)
#pragma unroll
    for (int r = 0; r < 4; ++r)
      merged[(size_t)(b * TT + qrow + r) * EMB + h * HD + nj * 16 + q15] = f2bf(o[nj][r]);

  // 5. zero strictly-upper tiles (drains at kernel end — never feeds a
  //    vmcnt drain; r15's in-loop variant regressed 33us by violating that)
  {
    const int zrow = tid >> 2, zc = (tid & 3) * 16;
    float* zbase = wout + ((size_t)bh * TT + qt * 128 + zrow) * TT + zc;
    const f32x4 z = (f32x4){0.f, 0.f, 0.f, 0.f};
    for (int kt = 2 * qt + 2; kt < TT / 64; ++kt) {
      float* p = zbase + kt * 64;
      *(f32x4*)(p)      = z;
      *(f32x4*)(p + 4)  = z;
      *(f32x4*)(p + 8)  = z;
      *(f32x4*)(p + 12) = z;
    }
  }
}

// ---------- host launcher ----------
extern "C" void kernel_launch(void* const* d_in, const int* in_sizes, int n_in,
                              void* d_out, int out_size, void* d_ws, size_t ws_size,
                              hipStream_t stream) {
  const float* x  = (const float*)d_in[0];
  const float* WQ = (const float*)d_in[2];
  const float* WK = (const float*)d_in[3];
  const float* WV = (const float*)d_in[4];
  const float* WO = (const float*)d_in[5];

  float* y    = (float*)d_out;                          // [B,T,E]
  float* wout = (float*)d_out + (size_t)NB * TT * EMB;  // [B,H,T,T]

  char* ws = (char*)d_ws;
  short* xb     = (short*)(ws + 0);          //  8,388,608 B
  short* wqkv   = (short*)(ws + 8388608);    //  6,291,456 B
  short* wob    = (short*)(ws + 14680064);   //  2,097,152 B
  short* qkvb   = (short*)(ws + 16777216);   // 25,165,824 B (V region unused)
  short* vtb    = (short*)(ws + 41943040);   //  8,388,608 B
  short* merged = (short*)(ws + 50331648);   //  8,388,608 B

  // 1. all fp32 -> bf16 conversions, one launch
  cvt_all<<<8192, 256, 0, stream>>>(x, WQ, WK, WV, WO, xb, wqkv, wob);

  // 2. packed QKV projection; V blocks write vtb[bh][d][t] directly
  gemm_nt<1><<<dim3(24, 32), 512, 0, stream>>>(xb, wqkv, qkvb, vtb,
                                               4096, 3072, 1024);

  // 3. fused attention (r13 structure: QBLK=128, CU-balanced, swapped QK^T,
  //    pair-processed, tail zero-fill)
  attn_fused<<<dim3(16, 32), 512, 0, stream>>>(qkvb, vtb, wout, merged);

  // 4. output projection
  gemm_nt<0><<<dim3(8, 32), 512, 0, stream>>>(merged, wob, y, nullptr,
                                              4096, 1024, 1024);
}